// Round 4
// baseline (143.625 us; speedup 1.0000x reference)
//
#include <hip/hip_runtime.h>

// ---------------------------------------------------------------------------
// metaLinear: y[t,o] = sum_j x2[t,j] * ( x1[t,:]@W[j*64+o,:] + bvec[j*64+o] )
//   T=16384, IN1=256, IN2=64 (j), OUT=64 (o).
// Round 4: j-split x2 for TLP (512 WGs -> 2 WGs/CU -> 2 waves/SIMD), WG =
// 128 tokens x 32 outputs (4 waves share identical W frags -> L1 dedup),
// barrier-free register j-loop with depth-2 k-half prefetch pipeline
// (wa[8]/wb[8]), bias via epilogue MFMA matmul, partial-sum reduce kernel.
// Host falls back to an unsplit launch if ws_size is too small.
// ---------------------------------------------------------------------------

#define FRAG_SHORTS 512                      // 64 lanes * 8 bf16
#define TILE_SHORTS (2 * 16 * FRAG_SHORTS)   // 16384 shorts per j (both oh)
#define WF_BYTES    (64 * 32768)             // 2 MiB fragment-ordered W
#define P_ELEMS     (16384 * 64)             // one partial slab (f32 elems)

typedef __bf16 bf16x8 __attribute__((ext_vector_type(8)));
typedef float  f32x16 __attribute__((ext_vector_type(16)));

static __device__ __forceinline__ unsigned short f2bf(float f) {
  union { float f; unsigned u; } v; v.f = f;
  unsigned r = v.u + 0x7FFFu + ((v.u >> 16) & 1u);   // RNE
  return (unsigned short)(r >> 16);
}

// Wf[((j*2+oh)*16 + ks)*512 + lane*8 + e] =
//     bf16( W[row = 64j+32oh+(lane&31)][col = 16ks + 8*(lane>>5) + e] )
__global__ void prep_w(const float* __restrict__ W, unsigned short* __restrict__ Wf) {
  int wv   = threadIdx.x >> 6;
  int lane = threadIdx.x & 63;
  int l31  = lane & 31;
  int lg   = lane >> 5;
  int task = blockIdx.x * 4 + wv;       // 0..2047
  int ks   = task & 15;
  int joh  = task >> 4;                 // j*2+oh
  int r    = 32 * joh + l31;
  int col  = ks * 16 + lg * 8;

  const float4* src = (const float4*)(W + (size_t)r * 256 + col);
  float4 a = src[0], b = src[1];
  ushort4 u0, u1;
  u0.x = f2bf(a.x); u0.y = f2bf(a.y); u0.z = f2bf(a.z); u0.w = f2bf(a.w);
  u1.x = f2bf(b.x); u1.y = f2bf(b.y); u1.z = f2bf(b.z); u1.w = f2bf(b.w);
  size_t fb = ((size_t)joh * 16 + ks) * FRAG_SHORTS;
  *(ushort4*)&Wf[fb + lane * 8 + 0] = u0;
  *(ushort4*)&Wf[fb + lane * 8 + 4] = u1;
}

// Grid: 128 tokTiles x 2 oh x njh. WG: 256 threads = 4 waves, wave wv owns
// tokens [tok0+32wv, +32) x outputs [32oh, +32), j in [jh*jcount, +jcount).
__global__ __launch_bounds__(256, 2)
void meta_main(const float* __restrict__ x1, const float* __restrict__ x2,
               const float* __restrict__ bvec,
               const unsigned short* __restrict__ Wf, float* __restrict__ outp,
               int njh, int jcount) {
  __shared__ unsigned short sX1[64 * 264];   // 33792 B: x1 staging / bvec cvt

  const int tid  = threadIdx.x;
  const int lane = tid & 63;
  const int wv   = tid >> 6;
  const int l31  = lane & 31;
  const int lg   = lane >> 5;

  const int tokTile = blockIdx.x / (2 * njh);
  const int rem     = blockIdx.x - tokTile * 2 * njh;
  const int oh      = rem / njh;
  const int jh      = rem - oh * njh;
  const int jb      = jh * jcount;
  const long tok0   = (long)tokTile * 128;

  // ---- prologue: two 64-token staging passes; wave wv reads its bfrags ----
  bf16x8 bfrag[16];
  for (int p = 0; p < 2; ++p) {
    const float4* src = (const float4*)(x1 + (tok0 + 64 * p) * 256);
    #pragma unroll
    for (int it = 0; it < 16; ++it) {
      int fi4 = it * 256 + tid;
      float4 v = src[fi4];
      int tl  = fi4 >> 6;
      int col = (fi4 & 63) * 4;
      ushort4 b;
      b.x = f2bf(v.x); b.y = f2bf(v.y); b.z = f2bf(v.z); b.w = f2bf(v.w);
      *(ushort4*)&sX1[tl * 264 + col] = b;
    }
    __syncthreads();
    if ((wv >> 1) == p) {
      const unsigned short* base = &sX1[((wv & 1) * 32 + l31) * 264 + lg * 8];
      #pragma unroll
      for (int ks = 0; ks < 16; ++ks)
        bfrag[ks] = *(const bf16x8*)(base + ks * 16);
    }
    __syncthreads();
  }

  // ---- barrier-free j-loop: depth-2 k-half register pipeline ----
  const unsigned short* wp = Wf + (size_t)jb * TILE_SHORTS + oh * 8192 + lane * 8;

  bf16x8 wa[8], wb[8];
  #pragma unroll
  for (int k = 0; k < 8; ++k) wa[k] = *(const bf16x8*)(wp + k * FRAG_SHORTS);
  #pragma unroll
  for (int k = 0; k < 8; ++k) wb[k] = *(const bf16x8*)(wp + (8 + k) * FRAG_SHORTS);

  f32x16 yacc;
  #pragma unroll
  for (int r = 0; r < 16; ++r) yacc[r] = 0.0f;

  const float4* x2q = (const float4*)(x2 + (tok0 + 32 * wv + l31) * 64);

  for (int jj = 0; jj < jcount; jj += 4) {
    float4 q = x2q[(jb + jj) >> 2];
    #pragma unroll
    for (int u = 0; u < 4; ++u) {
      float x2s = (u == 0) ? q.x : (u == 1) ? q.y : (u == 2) ? q.z : q.w;
      const unsigned short* np = wp + (size_t)(jj + u + 1) * TILE_SHORTS;
      const bool ok = (jj + u + 1) < jcount;

      f32x16 wlo, whi;
      #pragma unroll
      for (int r = 0; r < 16; ++r) { wlo[r] = 0.0f; whi[r] = 0.0f; }

      #pragma unroll
      for (int k = 0; k < 8; ++k)
        wlo = __builtin_amdgcn_mfma_f32_32x32x16_bf16(wa[k], bfrag[k], wlo, 0, 0, 0);
      if (ok) {                                  // prefetch half A of j+1
        #pragma unroll
        for (int k = 0; k < 8; ++k) wa[k] = *(const bf16x8*)(np + k * FRAG_SHORTS);
      }
      #pragma unroll
      for (int k = 0; k < 8; ++k)
        whi = __builtin_amdgcn_mfma_f32_32x32x16_bf16(wb[k], bfrag[8 + k], whi, 0, 0, 0);
      if (ok) {                                  // prefetch half B of j+1
        #pragma unroll
        for (int k = 0; k < 8; ++k) wb[k] = *(const bf16x8*)(np + (8 + k) * FRAG_SHORTS);
      }
      #pragma unroll
      for (int r = 0; r < 16; ++r)
        yacc[r] += x2s * (wlo[r] + whi[r]);
    }
  }

  // ---- bias epilogue (jh==0 WGs only): y += x2 @ Bmat, 4 MFMAs ----
  if (jh == 0) {
    __syncthreads();                             // reuse sX1
    #pragma unroll
    for (int c = 0; c < 4; ++c) {
      float4 v = ((const float4*)bvec)[c * 256 + tid];
      ushort4 u;
      u.x = f2bf(v.x); u.y = f2bf(v.y); u.z = f2bf(v.z); u.w = f2bf(v.w);
      *(ushort4*)&sX1[(c * 256 + tid) * 4] = u;
    }
    __syncthreads();
    const __bf16* bb = (const __bf16*)sX1;
    #pragma unroll
    for (int k = 0; k < 4; ++k) {
      bf16x8 Af, Bf;
      #pragma unroll
      for (int e = 0; e < 8; ++e)                // A[m=o][k'=j'] = bvec[j'*64+o]
        Af[e] = bb[(16 * k + 8 * lg + e) * 64 + 32 * oh + l31];
      const float* xr = x2 + (tok0 + 32 * wv + l31) * 64 + 16 * k + 8 * lg;
      float4 p0 = *(const float4*)xr;
      float4 p1 = *(const float4*)(xr + 4);
      Bf[0] = (__bf16)p0.x; Bf[1] = (__bf16)p0.y; Bf[2] = (__bf16)p0.z; Bf[3] = (__bf16)p0.w;
      Bf[4] = (__bf16)p1.x; Bf[5] = (__bf16)p1.y; Bf[6] = (__bf16)p1.z; Bf[7] = (__bf16)p1.w;
      yacc = __builtin_amdgcn_mfma_f32_32x32x16_bf16(Af, Bf, yacc, 0, 0, 0);
    }
  }

  // ---- store: D row o_local = (r&3)+8*(r>>2)+4*lg, col = token = l31 ----
  float* yout = outp + (size_t)jh * P_ELEMS + (tok0 + 32 * wv + l31) * 64 + oh * 32;
  #pragma unroll
  for (int q4 = 0; q4 < 4; ++q4) {
    float4 v;
    v.x = yacc[4 * q4 + 0]; v.y = yacc[4 * q4 + 1];
    v.z = yacc[4 * q4 + 2]; v.w = yacc[4 * q4 + 3];
    *(float4*)&yout[q4 * 8 + 4 * lg] = v;
  }
}

// out = P0 + P1 (float4-wide)
__global__ void reduce_add(const float* __restrict__ P, float* __restrict__ out) {
  int i = blockIdx.x * 256 + threadIdx.x;        // float4 index
  float4 a = ((const float4*)P)[i];
  float4 b = ((const float4*)(P + P_ELEMS))[i];
  float4 r;
  r.x = a.x + b.x; r.y = a.y + b.y; r.z = a.z + b.z; r.w = a.w + b.w;
  ((float4*)out)[i] = r;
}

extern "C" void kernel_launch(void* const* d_in, const int* in_sizes, int n_in,
                              void* d_out, int out_size, void* d_ws, size_t ws_size,
                              hipStream_t stream) {
  const float* x1 = (const float*)d_in[0];   // (4,4096,256) f32
  const float* x2 = (const float*)d_in[1];   // (4,4096,64)  f32
  const float* W  = (const float*)d_in[2];   // (4096,256)   f32
  const float* bv = (const float*)d_in[3];   // (4096,)      f32
  float* y = (float*)d_out;                  // (4,4096,64)  f32
  unsigned short* Wf = (unsigned short*)d_ws;

  prep_w<<<512, 256, 0, stream>>>(W, Wf);

  size_t need = (size_t)WF_BYTES + 2 * (size_t)P_ELEMS * 4;
  if (ws_size >= need) {
    float* P = (float*)((char*)d_ws + WF_BYTES);
    meta_main<<<512, 256, 0, stream>>>(x1, x2, bv, Wf, P, 2, 32);
    reduce_add<<<P_ELEMS / 4 / 256, 256, 0, stream>>>(P, y);
  } else {
    meta_main<<<256, 256, 0, stream>>>(x1, x2, bv, Wf, y, 1, 64);
  }
}

// Round 5
// 123.026 us; speedup vs baseline: 1.1674x; 1.1674x over previous
//
#include <hip/hip_runtime.h>

// ---------------------------------------------------------------------------
// metaLinear: y[t,o] = sum_j x2[t,j] * ( x1[t,:]@W[j*64+o,:] + bvec[j*64+o] )
//   T=16384, IN1=256, IN2=64 (j), OUT=64 (o).
// Round 5: A-frag register reuse x2 (wave = 64 tok x 32 o: each streamed W
// frag feeds 2 MFMAs -> A-BW demand 64 B/cyc/CU, within L1). K-split into
// two passes (ks 0-7 / 8-15; y is linear in w so partial-K products sum)
// keeps VGPR ~220 under the declared 256 cap (launch_bounds(256,1)).
// Barrier-free j-loop, depth-1-j register double buffer, j-split x2 for
// a 256-WG grid. Bias via epilogue MFMA matmul; partial-sum reduce kernel.
// ---------------------------------------------------------------------------

#define FRAG_SHORTS 512                      // 64 lanes * 8 bf16
#define TILE_SHORTS (2 * 16 * FRAG_SHORTS)   // shorts per j (both oh, 16 ks)
#define WF_BYTES    (64 * 32768)             // 2 MiB fragment-ordered W
#define P_ELEMS     (16384 * 64)             // one partial slab (f32 elems)
#define SX_STRIDE   136                      // shorts; 16B-aligned rows

typedef __bf16 bf16x8 __attribute__((ext_vector_type(8)));
typedef float  f32x16 __attribute__((ext_vector_type(16)));

static __device__ __forceinline__ unsigned short f2bf(float f) {
  union { float f; unsigned u; } v; v.f = f;
  unsigned r = v.u + 0x7FFFu + ((v.u >> 16) & 1u);   // RNE
  return (unsigned short)(r >> 16);
}

// Wf[((j*2+oh)*16 + ks)*512 + lane*8 + e] =
//     bf16( W[row = 64j+32oh+(lane&31)][col = 16ks + 8*(lane>>5) + e] )
__global__ void prep_w(const float* __restrict__ W, unsigned short* __restrict__ Wf) {
  int wv   = threadIdx.x >> 6;
  int lane = threadIdx.x & 63;
  int l31  = lane & 31;
  int lg   = lane >> 5;
  int task = blockIdx.x * 4 + wv;       // 0..2047
  int ks   = task & 15;
  int joh  = task >> 4;                 // j*2+oh
  int r    = 32 * joh + l31;
  int col  = ks * 16 + lg * 8;

  const float4* src = (const float4*)(W + (size_t)r * 256 + col);
  float4 a = src[0], b = src[1];
  ushort4 u0, u1;
  u0.x = f2bf(a.x); u0.y = f2bf(a.y); u0.z = f2bf(a.z); u0.w = f2bf(a.w);
  u1.x = f2bf(b.x); u1.y = f2bf(b.y); u1.z = f2bf(b.z); u1.w = f2bf(b.w);
  size_t fb = ((size_t)joh * 16 + ks) * FRAG_SHORTS;
  *(ushort4*)&Wf[fb + lane * 8 + 0] = u0;
  *(ushort4*)&Wf[fb + lane * 8 + 4] = u1;
}

// Grid: (T/128) x njh WGs. WG: 256 thr = 4 waves; wave wv: oh = wv>>1,
// tpair = wv&1 -> tokens [tok0 + tpair*64, +64) as two 32-token MFMA tiles,
// outputs [32*oh, +32), j in [jh*jcount, +jcount).
__global__ __launch_bounds__(256, 1)
void meta_main(const float* __restrict__ x1, const float* __restrict__ x2,
               const float* __restrict__ bvec,
               const unsigned short* __restrict__ Wf, float* __restrict__ outp,
               int njh, int jcount) {
  __shared__ unsigned short sX1[128 * SX_STRIDE];   // 34816 B

  const int tid   = threadIdx.x;
  const int lane  = tid & 63;
  const int wv    = tid >> 6;
  const int oh    = wv >> 1;
  const int tpair = wv & 1;
  const int l31   = lane & 31;
  const int lg    = lane >> 5;

  const int tokTile = blockIdx.x / njh;
  const int jh      = blockIdx.x - tokTile * njh;
  const int jb      = jh * jcount;
  const long tok0   = (long)tokTile * 128;

  const int t0 = tpair * 64 + l31;        // tile-0 token (local)
  const int t1 = t0 + 32;                 // tile-1 token (local)

  f32x16 yacc0, yacc1;
  #pragma unroll
  for (int r = 0; r < 16; ++r) { yacc0[r] = 0.0f; yacc1[r] = 0.0f; }

  const float4* x2q0 = (const float4*)(x2 + (tok0 + t0) * 64);
  const float4* x2q1 = (const float4*)(x2 + (tok0 + t1) * 64);

  for (int kp = 0; kp < 2; ++kp) {
    // ---- stage x1[tok0..+128][kp*128..+128] fp32 -> bf16, stride 136 ----
    __syncthreads();                      // prior pass's bfrag reads done
    {
      const float4* src = (const float4*)(x1 + tok0 * 256 + kp * 128);
      #pragma unroll
      for (int it = 0; it < 16; ++it) {
        int fi4 = it * 256 + tid;         // 4096 float4 = 128 rows x 32
        int row = fi4 >> 5;
        int c   = fi4 & 31;
        float4 v = src[(size_t)row * 64 + c];
        ushort4 b;
        b.x = f2bf(v.x); b.y = f2bf(v.y); b.z = f2bf(v.z); b.w = f2bf(v.w);
        *(ushort4*)&sX1[row * SX_STRIDE + c * 4] = b;
      }
    }
    __syncthreads();

    // ---- bfrags for this K-half: 2 token tiles x 8 ks ----
    bf16x8 bf0[8], bf1[8];
    #pragma unroll
    for (int kk = 0; kk < 8; ++kk) {
      bf0[kk] = *(const bf16x8*)&sX1[t0 * SX_STRIDE + kk * 16 + lg * 8];
      bf1[kk] = *(const bf16x8*)&sX1[t1 * SX_STRIDE + kk * 16 + lg * 8];
    }

    // ---- barrier-free j-loop, register dbuf, 16 MFMA per j ----
    const unsigned short* wp =
        Wf + ((size_t)(jb * 2 + oh) * 16 + kp * 8) * FRAG_SHORTS + lane * 8;

    bf16x8 bufA[8], bufB[8];
    #pragma unroll
    for (int kk = 0; kk < 8; ++kk)
      bufA[kk] = *(const bf16x8*)(wp + (size_t)kk * FRAG_SHORTS);

    auto jstep = [&](bf16x8 (&cur)[8], bf16x8 (&nxt)[8], int jnext, bool donext,
                     float q0s, float q1s) __attribute__((always_inline)) {
      if (donext) {                       // prefetch first: overlaps MFMAs
        const unsigned short* np = wp + (size_t)jnext * TILE_SHORTS;
        #pragma unroll
        for (int kk = 0; kk < 8; ++kk)
          nxt[kk] = *(const bf16x8*)(np + (size_t)kk * FRAG_SHORTS);
      }
      f32x16 w0, w1;
      #pragma unroll
      for (int r = 0; r < 16; ++r) { w0[r] = 0.0f; w1[r] = 0.0f; }
      #pragma unroll
      for (int kk = 0; kk < 8; ++kk) {
        w0 = __builtin_amdgcn_mfma_f32_32x32x16_bf16(cur[kk], bf0[kk], w0, 0, 0, 0);
        w1 = __builtin_amdgcn_mfma_f32_32x32x16_bf16(cur[kk], bf1[kk], w1, 0, 0, 0);
      }
      #pragma unroll
      for (int r = 0; r < 16; ++r) {
        yacc0[r] += q0s * w0[r];
        yacc1[r] += q1s * w1[r];
      }
    };

    for (int jj = 0; jj < jcount; jj += 4) {
      float4 q0 = x2q0[(jb + jj) >> 2];
      float4 q1 = x2q1[(jb + jj) >> 2];
      jstep(bufA, bufB, jj + 1, true, q0.x, q1.x);
      jstep(bufB, bufA, jj + 2, true, q0.y, q1.y);
      jstep(bufA, bufB, jj + 3, true, q0.z, q1.z);
      jstep(bufB, bufA, jj + 4, jj + 4 < jcount, q0.w, q1.w);
    }
  }

  // ---- bias epilogue (jh==0): y += x2 @ Bmat, 4 MFMAs per token tile ----
  if (jh == 0) {
    __syncthreads();                      // reuse sX1 (flat) for bf16 bvec
    #pragma unroll
    for (int c = 0; c < 4; ++c) {
      float4 v = ((const float4*)bvec)[c * 256 + tid];
      ushort4 u;
      u.x = f2bf(v.x); u.y = f2bf(v.y); u.z = f2bf(v.z); u.w = f2bf(v.w);
      *(ushort4*)&sX1[(c * 256 + tid) * 4] = u;
    }
    __syncthreads();
    const __bf16* bb = (const __bf16*)sX1;
    #pragma unroll
    for (int k = 0; k < 4; ++k) {
      bf16x8 Af;
      #pragma unroll
      for (int e = 0; e < 8; ++e)         // A[m=o][k'=j'] = bvec[j'*64+o]
        Af[e] = bb[(16 * k + 8 * lg + e) * 64 + 32 * oh + l31];
      const float* xr0 = x2 + (tok0 + t0) * 64 + 16 * k + 8 * lg;
      const float* xr1 = x2 + (tok0 + t1) * 64 + 16 * k + 8 * lg;
      float4 p0 = *(const float4*)xr0, p1 = *(const float4*)(xr0 + 4);
      float4 p2 = *(const float4*)xr1, p3 = *(const float4*)(xr1 + 4);
      bf16x8 Bf0, Bf1;
      Bf0[0] = (__bf16)p0.x; Bf0[1] = (__bf16)p0.y; Bf0[2] = (__bf16)p0.z; Bf0[3] = (__bf16)p0.w;
      Bf0[4] = (__bf16)p1.x; Bf0[5] = (__bf16)p1.y; Bf0[6] = (__bf16)p1.z; Bf0[7] = (__bf16)p1.w;
      Bf1[0] = (__bf16)p2.x; Bf1[1] = (__bf16)p2.y; Bf1[2] = (__bf16)p2.z; Bf1[3] = (__bf16)p2.w;
      Bf1[4] = (__bf16)p3.x; Bf1[5] = (__bf16)p3.y; Bf1[6] = (__bf16)p3.z; Bf1[7] = (__bf16)p3.w;
      yacc0 = __builtin_amdgcn_mfma_f32_32x32x16_bf16(Af, Bf0, yacc0, 0, 0, 0);
      yacc1 = __builtin_amdgcn_mfma_f32_32x32x16_bf16(Af, Bf1, yacc1, 0, 0, 0);
    }
  }

  // ---- store: D row o_local = (r&3)+8*(r>>2)+4*lg, col = token ----
  float* y0 = outp + (size_t)jh * P_ELEMS + (tok0 + t0) * 64 + oh * 32;
  float* y1 = outp + (size_t)jh * P_ELEMS + (tok0 + t1) * 64 + oh * 32;
  #pragma unroll
  for (int q4 = 0; q4 < 4; ++q4) {
    float4 v0, v1;
    v0.x = yacc0[4 * q4 + 0]; v0.y = yacc0[4 * q4 + 1];
    v0.z = yacc0[4 * q4 + 2]; v0.w = yacc0[4 * q4 + 3];
    v1.x = yacc1[4 * q4 + 0]; v1.y = yacc1[4 * q4 + 1];
    v1.z = yacc1[4 * q4 + 2]; v1.w = yacc1[4 * q4 + 3];
    *(float4*)&y0[q4 * 8 + 4 * lg] = v0;
    *(float4*)&y1[q4 * 8 + 4 * lg] = v1;
  }
}

// out = P0 + P1 (float4-wide)
__global__ void reduce_add(const float* __restrict__ P, float* __restrict__ out) {
  int i = blockIdx.x * 256 + threadIdx.x;        // float4 index
  float4 a = ((const float4*)P)[i];
  float4 b = ((const float4*)(P + P_ELEMS))[i];
  float4 r;
  r.x = a.x + b.x; r.y = a.y + b.y; r.z = a.z + b.z; r.w = a.w + b.w;
  ((float4*)out)[i] = r;
}

extern "C" void kernel_launch(void* const* d_in, const int* in_sizes, int n_in,
                              void* d_out, int out_size, void* d_ws, size_t ws_size,
                              hipStream_t stream) {
  const float* x1 = (const float*)d_in[0];   // (4,4096,256) f32
  const float* x2 = (const float*)d_in[1];   // (4,4096,64)  f32
  const float* W  = (const float*)d_in[2];   // (4096,256)   f32
  const float* bv = (const float*)d_in[3];   // (4096,)      f32
  float* y = (float*)d_out;                  // (4,4096,64)  f32
  unsigned short* Wf = (unsigned short*)d_ws;

  prep_w<<<512, 256, 0, stream>>>(W, Wf);

  size_t need = (size_t)WF_BYTES + 2 * (size_t)P_ELEMS * 4;
  if (ws_size >= need) {
    float* P = (float*)((char*)d_ws + WF_BYTES);
    meta_main<<<256, 256, 0, stream>>>(x1, x2, bv, Wf, P, 2, 32);
    reduce_add<<<P_ELEMS / 4 / 256, 256, 0, stream>>>(P, y);
  } else {
    meta_main<<<128, 256, 0, stream>>>(x1, x2, bv, Wf, y, 1, 64);
  }
}